// Round 1
// baseline (111.599 us; speedup 1.0000x reference)
//
#include <hip/hip_runtime.h>
#include <math.h>

// ---------------- workspace layout (bytes) ----------------
// [0)            double sum
// [16)           unsigned minkey[64]
// [16+256)       unsigned maxkey[64]
// [16+512)       float u7[7]   (separable 1-D gaussian weights)

__device__ __forceinline__ unsigned fkey(float f) {
    unsigned u = __float_as_uint(f);
    return (u & 0x80000000u) ? ~u : (u | 0x80000000u);
}
__device__ __forceinline__ float funkey(unsigned k) {
    return __uint_as_float((k & 0x80000000u) ? (k & 0x7FFFFFFFu) : ~k);
}

__global__ void init_ws(const float* __restrict__ w, float* __restrict__ u7,
                        unsigned* __restrict__ mink, unsigned* __restrict__ maxk,
                        double* __restrict__ sum) {
    int t = threadIdx.x;
    if (t == 0) *sum = 0.0;
    if (t < 64) { mink[t] = 0xFFFFFFFFu; maxk[t] = 0u; }
    if (t < 7) {
        float s = 0.f;
        for (int j = 0; j < 7; ++j) s += w[t * 7 + j];
        u7[t] = s;  // row sums of normalized 2-D window == 1-D weights
    }
}

// per-batch min/max of Y. 8 blocks per batch, 256 threads, float4 loads.
__global__ __launch_bounds__(256) void minmax_kernel(const float4* __restrict__ Y,
                                                     unsigned* __restrict__ mink,
                                                     unsigned* __restrict__ maxk) {
    int b = blockIdx.x >> 3, ch = blockIdx.x & 7;
    const float4* p = Y + (size_t)b * 65536 + (size_t)ch * 8192 + threadIdx.x;
    float lmin = INFINITY, lmax = -INFINITY;
#pragma unroll
    for (int i = 0; i < 32; ++i) {
        float4 v = p[(size_t)i * 256];
        lmin = fminf(lmin, fminf(fminf(v.x, v.y), fminf(v.z, v.w)));
        lmax = fmaxf(lmax, fmaxf(fmaxf(v.x, v.y), fmaxf(v.z, v.w)));
    }
#pragma unroll
    for (int off = 32; off; off >>= 1) {
        lmin = fminf(lmin, __shfl_down(lmin, off));
        lmax = fmaxf(lmax, __shfl_down(lmax, off));
    }
    if ((threadIdx.x & 63) == 0) {
        atomicMin(&mink[b], fkey(lmin));
        atomicMax(&maxk[b], fkey(lmax));
    }
}

// Main SSIM kernel.
// Tile: 256 cols (1 col/thread) x 64 output rows. Grid = 64 images * 2 colstrips * 8 rowstrips.
// Separable blur: horizontal from LDS row buffer (double-buffered), vertical via
// 7-deep register pipeline (all static indices).
__global__ __launch_bounds__(256) void ssim_kernel(const float* __restrict__ X,
                                                   const float* __restrict__ Yg,
                                                   const float* __restrict__ u7,
                                                   const unsigned* __restrict__ mink,
                                                   const unsigned* __restrict__ maxk,
                                                   double* __restrict__ sum) {
    __shared__ float xs[2][264];
    __shared__ float ys[2][264];
    __shared__ float warpsum[4];

    const int blk = blockIdx.x;
    const int b = blk >> 4;        // image
    const int sub = blk & 15;
    const int cs = sub & 1;        // col strip (0..1)
    const int rs = sub >> 1;       // row strip (0..7)
    const int c0 = cs * 256;
    const int r0 = rs * 64;
    const int t = threadIdx.x;

    float u[7];
#pragma unroll
    for (int i = 0; i < 7; ++i) u[i] = u7[i];

    const float dr = funkey(maxk[b]) - funkey(mink[b]);
    float C1 = 0.01f * dr; C1 *= C1;
    float C2 = 0.03f * dr; C2 *= C2;
    const float cn = 49.f / 48.f;

    const float* __restrict__ Xb = X  + (size_t)b * 262144;
    const float* __restrict__ Yb = Yg + (size_t)b * 262144;

    // vertical register pipelines (static indexing only)
    float px[7], py[7], pxx[7], pyy[7], pxy[7];
#pragma unroll
    for (int k = 0; k < 7; ++k) { px[k]=0.f; py[k]=0.f; pxx[k]=0.f; pyy[k]=0.f; pxy[k]=0.f; }

    float ssacc = 0.f;

    // row loader: LDS index l covers global cols c0-3 .. c0+258 (262 entries)
    auto load_row = [&](int r, int p) {
        {
            int l = t;
            int c = c0 - 3 + l;
            float xv = 0.f, yv = 0.f;
            if (r >= 0 && r < 512 && c >= 0 && c < 512) {
                xv = Xb[r * 512 + c];
                yv = Yb[r * 512 + c];
            }
            xs[p][l] = xv; ys[p][l] = yv;
        }
        if (t < 6) {
            int l = 256 + t;
            int c = c0 - 3 + l;
            float xv = 0.f, yv = 0.f;
            if (r >= 0 && r < 512 && c < 512) {
                xv = Xb[r * 512 + c];
                yv = Yb[r * 512 + c];
            }
            xs[p][l] = xv; ys[p][l] = yv;
        }
    };

    load_row(r0 - 3, 0);
    __syncthreads();

    for (int j = 0; j < 70; ++j) {
        const int p = j & 1;
        if (j < 69) load_row(r0 - 3 + j + 1, p ^ 1);

        // horizontal blur of x, y, x^2, y^2, xy at row r0-3+j
        float hx = 0.f, hy = 0.f, hxx = 0.f, hyy = 0.f, hxy = 0.f;
#pragma unroll
        for (int k = 0; k < 7; ++k) {
            float xv = xs[p][t + k];
            float yv = ys[p][t + k];
            float wx = u[k] * xv;
            float wy = u[k] * yv;
            hx += wx;
            hy += wy;
            hxx = fmaf(wx, xv, hxx);
            hxy = fmaf(wx, yv, hxy);
            hyy = fmaf(wy, yv, hyy);
        }

        // push into vertical pipeline
#pragma unroll
        for (int k = 0; k < 6; ++k) {
            px[k] = px[k + 1]; py[k] = py[k + 1];
            pxx[k] = pxx[k + 1]; pyy[k] = pyy[k + 1]; pxy[k] = pxy[k + 1];
        }
        px[6] = hx; py[6] = hy; pxx[6] = hxx; pyy[6] = hyy; pxy[6] = hxy;

        if (j >= 6) {
            float mux = 0.f, muy = 0.f, mxx = 0.f, myy = 0.f, mxy = 0.f;
#pragma unroll
            for (int k = 0; k < 7; ++k) {
                mux = fmaf(u[k], px[k], mux);
                muy = fmaf(u[k], py[k], muy);
                mxx = fmaf(u[k], pxx[k], mxx);
                myy = fmaf(u[k], pyy[k], myy);
                mxy = fmaf(u[k], pxy[k], mxy);
            }
            float mux2 = mux * mux, muy2 = muy * muy, muxy = mux * muy;
            float sxx = (mxx - mux2) * cn;
            float syy = (myy - muy2) * cn;
            float sxy = (mxy - muxy) * cn;
            float num = (2.f * muxy + C1) * (2.f * sxy + C2);
            float den = (mux2 + muy2 + C1) * (sxx + syy + C2);
            ssacc += num / den;
        }
        __syncthreads();
    }

    // block reduction: wave shuffle -> LDS -> one double atomic per block
#pragma unroll
    for (int off = 32; off; off >>= 1) ssacc += __shfl_down(ssacc, off);
    if ((t & 63) == 0) warpsum[t >> 6] = ssacc;
    __syncthreads();
    if (t == 0) {
        double s = (double)warpsum[0] + (double)warpsum[1] +
                   (double)warpsum[2] + (double)warpsum[3];
        atomicAdd(sum, s);
    }
}

__global__ void finalize_kernel(const double* __restrict__ sum, float* __restrict__ out) {
    out[0] = (float)(1.0 - (*sum) / (64.0 * 512.0 * 512.0));
}

extern "C" void kernel_launch(void* const* d_in, const int* in_sizes, int n_in,
                              void* d_out, int out_size, void* d_ws, size_t ws_size,
                              hipStream_t stream) {
    const float* X = (const float*)d_in[0];
    const float* Y = (const float*)d_in[1];
    const float* W = (const float*)d_in[2];

    char* ws = (char*)d_ws;
    double* sum = (double*)(ws + 0);
    unsigned* mink = (unsigned*)(ws + 16);
    unsigned* maxk = (unsigned*)(ws + 16 + 256);
    float* u7 = (float*)(ws + 16 + 512);

    init_ws<<<1, 64, 0, stream>>>(W, u7, mink, maxk, sum);
    minmax_kernel<<<512, 256, 0, stream>>>((const float4*)Y, mink, maxk);
    ssim_kernel<<<1024, 256, 0, stream>>>(X, Y, u7, mink, maxk, sum);
    finalize_kernel<<<1, 1, 0, stream>>>(sum, (float*)d_out);
}